// Round 11
// baseline (679.113 us; speedup 1.0000x reference)
//
#include <hip/hip_runtime.h>
#include <cstddef>

// W-MSA fused kernel: projections on MFMA (split-bf16 3-pass), attention on fp32 VALU.
// Round-10 deltas vs round-9 (each justified by counter decomposition):
//  - s_xw XOR-swizzled at 16B-unit granularity: u' = u ^ ((row>>1)&7).
//    Fixes pool-read 2x bank conflicts (even-row+even-unit -> even class) while
//    keeping Q/O-frag, attention-q4, and linear writeout at the LDS floor
//    (verified by enumeration of bank classes).
//  - s_k/s_v leading stride 192 -> 196 floats (write banks 4-way -> floor).
//  - O output staged in s_xw then written coalesced (768 B/pixel contiguous):
//    kills ~100 MB of partial-line RMW (WRITE_SIZE 304->~205 MB).
//
// MFMA 16x16x32 bf16 layouts (verified, learn_hip m89/m91):
//   A: lane l holds A[row=l&15][k=(l>>4)*8+j]; B: B[k=(l>>4)*8+j][col=l&15]
//   C/D: lane l, reg r -> row=(l>>4)*4+r, col=l&15

#define XSTR 196   // 49 16B-units/row: units 0..47 data (swizzle-closed), 48 pad
#define KSTR 196

typedef __attribute__((ext_vector_type(8))) short s16x8;   // 8 bf16 (4 VGPRs)
typedef __attribute__((ext_vector_type(4))) float f32x4;   // MFMA acc

__device__ __forceinline__ short f2bf(float f) {           // RNE fp32 -> bf16
    unsigned u = __float_as_uint(f);
    u = u + 0x7fffu + ((u >> 16) & 1u);
    return (short)(u >> 16);
}
__device__ __forceinline__ float bf2f(short h) {
    return __uint_as_float(((unsigned)(unsigned short)h) << 16);
}
__device__ __forceinline__ int swzu(int row, int u) {      // s_xw unit swizzle
    return u ^ ((row >> 1) & 7);
}

// d_ws layout (shorts): [mat(4)][hi|lo][ct(12)][kc(6)][lane(64)][8]
#define MAT_S 73728
#define LO_S  36864
#define CT_S   3072
#define KC_S    512

__global__ __launch_bounds__(256)
void prep_w(const float* __restrict__ Wq, const float* __restrict__ Wk,
            const float* __restrict__ Wv, const float* __restrict__ Wo,
            unsigned short* __restrict__ ws)
{
    const int t = blockIdx.x * 256 + threadIdx.x;
    if (t >= 4 * 12 * 6 * 64) return;
    const int lane = t & 63;
    const int kc = (t >> 6) % 6;
    const int ct = (t / 384) % 12;
    const int m  = t / 4608;
    const float* W = (m == 0) ? Wq : (m == 1) ? Wk : (m == 2) ? Wv : Wo;
    const int n  = ct * 16 + (lane & 15);
    const int k0 = kc * 32 + ((lane >> 4) * 8);
    alignas(16) unsigned short hi[8];
    alignas(16) unsigned short lo[8];
    #pragma unroll
    for (int j = 0; j < 8; ++j) {
        const float f = W[(size_t)(k0 + j) * 192 + n];
        const short h = f2bf(f);
        hi[j] = (unsigned short)h;
        lo[j] = (unsigned short)f2bf(f - bf2f(h));
    }
    unsigned short* dst = ws + (size_t)m * MAT_S + ct * CT_S + kc * KC_S + lane * 8;
    *reinterpret_cast<uint4*>(dst)        = *reinterpret_cast<const uint4*>(hi);
    *reinterpret_cast<uint4*>(dst + LO_S) = *reinterpret_cast<const uint4*>(lo);
}

__global__ __launch_bounds__(256, 2)
void wmsa_fused(const float* __restrict__ x,
                const float* __restrict__ bq, const float* __restrict__ bk,
                const float* __restrict__ bv, const float* __restrict__ bo,
                const float* __restrict__ rt,
                const unsigned short* __restrict__ ws,
                float* __restrict__ out)
{
    __shared__ alignas(16) float s_xw[64 * XSTR];   // rolled x -> Q -> attn out -> O (swizzled)
    __shared__ alignas(16) float s_k [16 * KSTR];
    __shared__ alignas(16) float s_v [16 * KSTR];
    __shared__ alignas(16) float s_rt[6 * 225];

    const int tid  = threadIdx.x;
    const int widx = blockIdx.x;
    const int b  = widx >> 10;
    const int wh = (widx >> 5) & 31;
    const int wc = widx & 31;

    // ---- Phase 0: load rolled window (roll -4,-4) + rel_table, swizzled store ----
    for (int idx = tid; idx < 64 * 48; idx += 256) {
        const int pix = idx / 48;
        const int c4  = idx - pix * 48;
        const int i = pix >> 3, j = pix & 7;
        const int row = (wh * 8 + i + 4) & 255;
        const int col = (wc * 8 + j + 4) & 255;
        const float4 v = *reinterpret_cast<const float4*>(
            x + ((size_t)((b * 256 + row) * 256 + col)) * 192 + c4 * 4);
        reinterpret_cast<float4*>(&s_xw[pix * XSTR])[swzu(pix, c4)] = v;
    }
    for (int idx = tid; idx < 6 * 225; idx += 256) s_rt[idx] = rt[idx];
    __syncthreads();

    const int lane = tid & 63;
    const int w    = tid >> 6;
    const int wm   = w >> 1;        // M-half (rows 32*wm..) for Q/O
    const int wn   = w & 1;         // N-half (ct 6*wn..)    for Q/O
    const int g    = lane >> 4;     // k-group within fragment
    const int c15  = lane & 15;

    // ---- KV A-fragments: pooled xd[kv=c15][k], fused 2x2 max-pool ----
    s16x8 kah[6], kal[6];
    {
        const int p0 = (c15 >> 2) * 16 + (c15 & 3) * 2;
        #pragma unroll
        for (int kc = 0; kc < 6; ++kc) {
            const int u0 = kc * 8 + g * 2;
            float4 m0, m1;
            {
                const float4 a0 = reinterpret_cast<const float4*>(&s_xw[(p0    ) * XSTR])[swzu(p0    , u0)];
                const float4 b0 = reinterpret_cast<const float4*>(&s_xw[(p0 + 1) * XSTR])[swzu(p0 + 1, u0)];
                const float4 c0 = reinterpret_cast<const float4*>(&s_xw[(p0 + 8) * XSTR])[swzu(p0 + 8, u0)];
                const float4 d0 = reinterpret_cast<const float4*>(&s_xw[(p0 + 9) * XSTR])[swzu(p0 + 9, u0)];
                m0.x = fmaxf(fmaxf(a0.x, b0.x), fmaxf(c0.x, d0.x));
                m0.y = fmaxf(fmaxf(a0.y, b0.y), fmaxf(c0.y, d0.y));
                m0.z = fmaxf(fmaxf(a0.z, b0.z), fmaxf(c0.z, d0.z));
                m0.w = fmaxf(fmaxf(a0.w, b0.w), fmaxf(c0.w, d0.w));
            }
            {
                const float4 a1 = reinterpret_cast<const float4*>(&s_xw[(p0    ) * XSTR])[swzu(p0    , u0 + 1)];
                const float4 b1 = reinterpret_cast<const float4*>(&s_xw[(p0 + 1) * XSTR])[swzu(p0 + 1, u0 + 1)];
                const float4 c1 = reinterpret_cast<const float4*>(&s_xw[(p0 + 8) * XSTR])[swzu(p0 + 8, u0 + 1)];
                const float4 d1 = reinterpret_cast<const float4*>(&s_xw[(p0 + 9) * XSTR])[swzu(p0 + 9, u0 + 1)];
                m1.x = fmaxf(fmaxf(a1.x, b1.x), fmaxf(c1.x, d1.x));
                m1.y = fmaxf(fmaxf(a1.y, b1.y), fmaxf(c1.y, d1.y));
                m1.z = fmaxf(fmaxf(a1.z, b1.z), fmaxf(c1.z, d1.z));
                m1.w = fmaxf(fmaxf(a1.w, b1.w), fmaxf(c1.w, d1.w));
            }
            const float mv[8] = {m0.x, m0.y, m0.z, m0.w, m1.x, m1.y, m1.z, m1.w};
            #pragma unroll
            for (int j = 0; j < 8; ++j) {
                const short h = f2bf(mv[j]);
                kah[kc][j] = h;
                kal[kc][j] = f2bf(mv[j] - bf2f(h));
            }
        }
    }

    // ---- K/V GEMM (MFMA): waves 0,1 -> K (ct 0..5 / 6..11); waves 2,3 -> V ----
    {
        const int isV = (w >> 1) & 1;
        const unsigned short* wsm = ws + (size_t)(1 + isV) * MAT_S;
        const float* bias = isV ? bv : bk;
        float* sdst = isV ? s_v : s_k;
        const int ct0 = (w & 1) * 6;
        #pragma unroll
        for (int ctl = 0; ctl < 6; ++ctl) {
            const int ct = ct0 + ctl;
            const unsigned short* bp = wsm + ct * CT_S + lane * 8;
            f32x4 a0 = {0.f,0.f,0.f,0.f}, a1 = a0, a2 = a0;
            #pragma unroll
            for (int kc = 0; kc < 6; ++kc) {
                const s16x8 bh = *reinterpret_cast<const s16x8*>(bp + kc * KC_S);
                const s16x8 bl = *reinterpret_cast<const s16x8*>(bp + kc * KC_S + LO_S);
                a0 = __builtin_amdgcn_mfma_f32_16x16x32_bf16(kah[kc], bh, a0, 0, 0, 0);
                a1 = __builtin_amdgcn_mfma_f32_16x16x32_bf16(kal[kc], bh, a1, 0, 0, 0);
                a2 = __builtin_amdgcn_mfma_f32_16x16x32_bf16(kah[kc], bl, a2, 0, 0, 0);
            }
            const float bb = bias[ct * 16 + c15];
            #pragma unroll
            for (int r = 0; r < 4; ++r)     // C: col=c15, row=g*4+r
                sdst[(g * 4 + r) * KSTR + ct * 16 + c15] = a0[r] + a1[r] + a2[r] + bb;
        }
    }

    // ---- Q A-fragments (rows 32*wm..+31; s_xw still holds original x) ----
    s16x8 qah[2][6], qal[2][6];
    #pragma unroll
    for (int mt = 0; mt < 2; ++mt) {
        const int rb = wm * 32 + mt * 16 + c15;
        #pragma unroll
        for (int kc = 0; kc < 6; ++kc) {
            const int u0 = kc * 8 + g * 2;
            const float4 f0 = reinterpret_cast<const float4*>(&s_xw[rb * XSTR])[swzu(rb, u0)];
            const float4 f1 = reinterpret_cast<const float4*>(&s_xw[rb * XSTR])[swzu(rb, u0 + 1)];
            const float fv[8] = {f0.x, f0.y, f0.z, f0.w, f1.x, f1.y, f1.z, f1.w};
            #pragma unroll
            for (int j = 0; j < 8; ++j) {
                const short h = f2bf(fv[j]);
                qah[mt][kc][j] = h;
                qal[mt][kc][j] = f2bf(fv[j] - bf2f(h));
            }
        }
    }
    __syncthreads();   // all frags built -> s_xw may be overwritten

    // ---- Q GEMM (MFMA), in-place into s_xw (disjoint row/col tiles per wave) ----
    {
        #pragma unroll
        for (int ctl = 0; ctl < 6; ++ctl) {
            const int ct = wn * 6 + ctl;
            const unsigned short* bp = ws + ct * CT_S + lane * 8;   // Wq = mat 0
            const float bb = bq[ct * 16 + c15];
            const int uq = ct * 4 + (c15 >> 2);
            const int eq = c15 & 3;
            #pragma unroll
            for (int mt = 0; mt < 2; ++mt) {
                f32x4 a0 = {0.f,0.f,0.f,0.f}, a1 = a0, a2 = a0;
                #pragma unroll
                for (int kc = 0; kc < 6; ++kc) {
                    const s16x8 bh = *reinterpret_cast<const s16x8*>(bp + kc * KC_S);
                    const s16x8 bl = *reinterpret_cast<const s16x8*>(bp + kc * KC_S + LO_S);
                    a0 = __builtin_amdgcn_mfma_f32_16x16x32_bf16(qah[mt][kc], bh, a0, 0, 0, 0);
                    a1 = __builtin_amdgcn_mfma_f32_16x16x32_bf16(qal[mt][kc], bh, a1, 0, 0, 0);
                    a2 = __builtin_amdgcn_mfma_f32_16x16x32_bf16(qah[mt][kc], bl, a2, 0, 0, 0);
                }
                #pragma unroll
                for (int r = 0; r < 4; ++r) {
                    const int p = wm * 32 + mt * 16 + g * 4 + r;
                    s_xw[p * XSTR + swzu(p, uq) * 4 + eq] = a0[r] + a1[r] + a2[r] + bb;
                }
            }
        }
    }
    __syncthreads();

    // ---- Attention: fp32 VALU, one thread per (head, query) ----
    {
        const float scale = 0.17677669529663687f;  // 32^-0.5
        const bool lastrow = (wh == 31);
        const bool lastcol = (wc == 31);
        #pragma unroll
        for (int pass = 0; pass < 2; ++pass) {
            const int pair = tid + pass * 256;
            if (pair < 384) {
                const int h = pair >> 6;
                const int p = pair & 63;
                const int pi = p >> 3, pj = p & 7;

                float4 q4[8];
                #pragma unroll
                for (int c4 = 0; c4 < 8; ++c4)
                    q4[c4] = reinterpret_cast<const float4*>(&s_xw[p * XSTR])[swzu(p, h * 8 + c4)];

                float sc[16];
                #pragma unroll
                for (int q_ = 0; q_ < 16; ++q_) {
                    float s = 0.f;
                    #pragma unroll
                    for (int c4 = 0; c4 < 8; ++c4) {
                        const float4 k4 = *reinterpret_cast<const float4*>(
                            &s_k[q_ * KSTR + h * 32 + c4 * 4]);
                        s = fmaf(q4[c4].x, k4.x, s);
                        s = fmaf(q4[c4].y, k4.y, s);
                        s = fmaf(q4[c4].z, k4.z, s);
                        s = fmaf(q4[c4].w, k4.w, s);
                    }
                    s *= scale;
                    const int qi = q_ >> 3, qj = q_ & 7;     // bias quirk: 8-wide coords
                    s += s_rt[h * 225 + (pi - qi + 7) * 15 + (pj - qj + 7)];
                    const int ki = q_ >> 2, kj = q_ & 3;     // mask: 4-wide coords
                    const bool msk = (lastrow && ((pi < 4) != (ki < 2))) ||
                                     (lastcol && ((pj < 4) != (kj < 2)));
                    sc[q_] = msk ? -1e30f : s;
                }

                float m = sc[0];
                #pragma unroll
                for (int q_ = 1; q_ < 16; ++q_) m = fmaxf(m, sc[q_]);
                float sum = 0.f;
                #pragma unroll
                for (int q_ = 0; q_ < 16; ++q_) { sc[q_] = __expf(sc[q_] - m); sum += sc[q_]; }
                const float inv = 1.0f / sum;
                #pragma unroll
                for (int q_ = 0; q_ < 16; ++q_) sc[q_] *= inv;

                #pragma unroll
                for (int c4 = 0; c4 < 8; ++c4) {
                    float ox = 0.f, oy = 0.f, oz = 0.f, ow = 0.f;
                    #pragma unroll
                    for (int q_ = 0; q_ < 16; ++q_) {
                        const float4 v4 = *reinterpret_cast<const float4*>(
                            &s_v[q_ * KSTR + h * 32 + c4 * 4]);
                        ox = fmaf(sc[q_], v4.x, ox);
                        oy = fmaf(sc[q_], v4.y, oy);
                        oz = fmaf(sc[q_], v4.z, oz);
                        ow = fmaf(sc[q_], v4.w, ow);
                    }
                    float4 o4; o4.x = ox; o4.y = oy; o4.z = oz; o4.w = ow;
                    reinterpret_cast<float4*>(&s_xw[p * XSTR])[swzu(p, h * 8 + c4)] = o4;
                }
            }
        }
    }
    __syncthreads();

    // ---- O A-fragments from attention output (own stripe, all channels) ----
    s16x8 oah[2][6], oal[2][6];
    #pragma unroll
    for (int mt = 0; mt < 2; ++mt) {
        const int rb = wm * 32 + mt * 16 + c15;
        #pragma unroll
        for (int kc = 0; kc < 6; ++kc) {
            const int u0 = kc * 8 + g * 2;
            const float4 f0 = reinterpret_cast<const float4*>(&s_xw[rb * XSTR])[swzu(rb, u0)];
            const float4 f1 = reinterpret_cast<const float4*>(&s_xw[rb * XSTR])[swzu(rb, u0 + 1)];
            const float fv[8] = {f0.x, f0.y, f0.z, f0.w, f1.x, f1.y, f1.z, f1.w};
            #pragma unroll
            for (int j = 0; j < 8; ++j) {
                const short h = f2bf(fv[j]);
                oah[mt][kc][j] = h;
                oal[mt][kc][j] = f2bf(fv[j] - bf2f(h));
            }
        }
    }
    __syncthreads();   // all O-frags read before any staged write overwrites s_xw

    // ---- O GEMM (MFMA) -> staged into s_xw (swizzled) ----
    {
        const unsigned short* wsm = ws + (size_t)3 * MAT_S;   // Wo = mat 3
        #pragma unroll
        for (int ctl = 0; ctl < 6; ++ctl) {
            const int ct = wn * 6 + ctl;
            const unsigned short* bp = wsm + ct * CT_S + lane * 8;
            const float bb = bo[ct * 16 + c15];
            const int uo = ct * 4 + (c15 >> 2);
            const int eo = c15 & 3;
            #pragma unroll
            for (int mt = 0; mt < 2; ++mt) {
                f32x4 a0 = {0.f,0.f,0.f,0.f}, a1 = a0, a2 = a0;
                #pragma unroll
                for (int kc = 0; kc < 6; ++kc) {
                    const s16x8 bh = *reinterpret_cast<const s16x8*>(bp + kc * KC_S);
                    const s16x8 bl = *reinterpret_cast<const s16x8*>(bp + kc * KC_S + LO_S);
                    a0 = __builtin_amdgcn_mfma_f32_16x16x32_bf16(oah[mt][kc], bh, a0, 0, 0, 0);
                    a1 = __builtin_amdgcn_mfma_f32_16x16x32_bf16(oal[mt][kc], bh, a1, 0, 0, 0);
                    a2 = __builtin_amdgcn_mfma_f32_16x16x32_bf16(oah[mt][kc], bl, a2, 0, 0, 0);
                }
                #pragma unroll
                for (int r = 0; r < 4; ++r) {
                    const int p = wm * 32 + mt * 16 + g * 4 + r;
                    s_xw[p * XSTR + swzu(p, uo) * 4 + eo] = a0[r] + a1[r] + a2[r] + bb;
                }
            }
        }
    }
    __syncthreads();

    // ---- Final coalesced writeout with roll-back (+4,+4): 768 B/pixel dense ----
    #pragma unroll
    for (int it = 0; it < 12; ++it) {
        const int idx = tid + it * 256;
        const int pix = idx / 48;
        const int c4  = idx - pix * 48;
        const float4 v = reinterpret_cast<const float4*>(&s_xw[pix * XSTR])[swzu(pix, c4)];
        const int i = pix >> 3, j = pix & 7;
        const int row = (wh * 8 + i + 4) & 255;
        const int col = (wc * 8 + j + 4) & 255;
        *reinterpret_cast<float4*>(
            out + ((size_t)((b * 256 + row) * 256 + col)) * 192 + c4 * 4) = v;
    }
}

extern "C" void kernel_launch(void* const* d_in, const int* in_sizes, int n_in,
                              void* d_out, int out_size, void* d_ws, size_t ws_size,
                              hipStream_t stream) {
    (void)in_sizes; (void)n_in; (void)out_size; (void)ws_size;
    const float* x  = (const float*)d_in[0];
    const float* Wq = (const float*)d_in[1];
    const float* bq = (const float*)d_in[2];
    const float* Wk = (const float*)d_in[3];
    const float* bk = (const float*)d_in[4];
    const float* Wv = (const float*)d_in[5];
    const float* bv = (const float*)d_in[6];
    const float* Wo = (const float*)d_in[7];
    const float* bo = (const float*)d_in[8];
    const float* rt = (const float*)d_in[9];
    float* out = (float*)d_out;
    unsigned short* ws = (unsigned short*)d_ws;   // needs 589824 B

    hipLaunchKernelGGL(prep_w, dim3(72), dim3(256), 0, stream, Wq, Wk, Wv, Wo, ws);
    hipLaunchKernelGGL(wmsa_fused, dim3(4096), dim3(256), 0, stream,
                       x, bq, bk, bv, bo, rt, ws, out);
}